// Round 2
// baseline (6624.266 us; speedup 1.0000x reference)
//
#include <hip/hip_runtime.h>
#include <float.h>

#define NB 16
#define NP 4096
#define NM 1024
#define NK 32
#define CIN 64
#define C3 128
#define CNT (NB*NM*NK)
#define EPSV 1e-5f

// Exact, contraction-free squared distance: matches numpy/JAX float32
// elementwise-square + left-to-right sum bit-for-bit. Discrete selections
// (FPS argmax, KNN k-th boundary) depend on exact bit patterns.
__device__ __forceinline__ float sqdist3(float dx, float dy, float dz) {
    return __fadd_rn(__fadd_rn(__fmul_rn(dx, dx), __fmul_rn(dy, dy)), __fmul_rn(dz, dz));
}

// ---------------------------------------------------------------- FPS
__global__ __launch_bounds__(512) void fps_kernel(const float* __restrict__ xyz,
                                                  int* __restrict__ fps_idx,
                                                  float* __restrict__ newxyz) {
    const int b = blockIdx.x;
    const int t = threadIdx.x;
    const float* xb = xyz + (size_t)b * NP * 3;
    float px[8], py[8], pz[8], dist[8];
#pragma unroll
    for (int j = 0; j < 8; ++j) {
        int n = t + 512 * j;
        px[j] = xb[n*3+0]; py[j] = xb[n*3+1]; pz[j] = xb[n*3+2];
        dist[j] = 1e10f;
    }
    __shared__ float cent[3];
    __shared__ float redv[8];
    __shared__ int   redi[8];
    int cur = 0;
    for (int it = 0; it < NM; ++it) {
        if (t == (cur & 511)) {
            int j = cur >> 9;
            cent[0] = px[j]; cent[1] = py[j]; cent[2] = pz[j];
            size_t o = ((size_t)b * NM + it) * 3;
            newxyz[o+0] = px[j]; newxyz[o+1] = py[j]; newxyz[o+2] = pz[j];
            fps_idx[b*NM + it] = cur;
        }
        __syncthreads();
        float cx = cent[0], cy = cent[1], cz = cent[2];
        float best = -1.0f; int bi = 0;
#pragma unroll
        for (int j = 0; j < 8; ++j) {
            float d = sqdist3(px[j]-cx, py[j]-cy, pz[j]-cz);
            float nd = fminf(dist[j], d);
            dist[j] = nd;
            if (nd > best) { best = nd; bi = t + 512*j; }   // ascending n: > keeps lowest idx
        }
#pragma unroll
        for (int off = 32; off > 0; off >>= 1) {
            float ov = __shfl_down(best, off, 64);
            int   oi = __shfl_down(bi,   off, 64);
            if (ov > best || (ov == best && oi < bi)) { best = ov; bi = oi; }
        }
        if ((t & 63) == 0) { redv[t>>6] = best; redi[t>>6] = bi; }
        __syncthreads();
        float bv = redv[0]; int bbi = redi[0];
#pragma unroll
        for (int w = 1; w < 8; ++w) {
            float v = redv[w]; int i2 = redi[w];
            if (v > bv || (v == bv && i2 < bbi)) { bv = v; bbi = i2; }
        }
        cur = bbi;   // every thread computes identically
    }
}

// ---------------------------------------------------------------- KNN
__global__ __launch_bounds__(256) void knn_kernel(const float* __restrict__ xyz,
                                                  const float* __restrict__ newxyz,
                                                  int* __restrict__ knn_idx) {
    const int g = blockIdx.x;
    const int b = g >> 10, m = g & (NM-1);
    const int t = threadIdx.x;
    const float* xb = xyz + (size_t)b * NP * 3;
    __shared__ float dist[NP];
    __shared__ float rv[4];
    __shared__ int   ri[4];
    size_t co = ((size_t)b * NM + m) * 3;
    float cx = newxyz[co+0], cy = newxyz[co+1], cz = newxyz[co+2];
#pragma unroll
    for (int j = 0; j < 16; ++j) {
        int n = t + 256*j;
        dist[n] = sqdist3(cx - xb[n*3+0], cy - xb[n*3+1], cz - xb[n*3+2]);
    }
    __syncthreads();
    for (int s = 0; s < NK; ++s) {
        float best = FLT_MAX; int bi = 0;
#pragma unroll
        for (int j = 0; j < 16; ++j) {
            int n = t + 256*j;
            float d = dist[n];
            if (d < best) { best = d; bi = n; }     // ascending n: < keeps lowest idx
        }
#pragma unroll
        for (int off = 32; off > 0; off >>= 1) {
            float ov = __shfl_down(best, off, 64);
            int   oi = __shfl_down(bi,   off, 64);
            if (ov < best || (ov == best && oi < bi)) { best = ov; bi = oi; }
        }
        if ((t & 63) == 0) { rv[t>>6] = best; ri[t>>6] = bi; }
        __syncthreads();
        float bv = rv[0]; int bbi = ri[0];
#pragma unroll
        for (int w = 1; w < 4; ++w) {
            float v = rv[w]; int i2 = ri[w];
            if (v < bv || (v == bv && i2 < bbi)) { bv = v; bbi = i2; }
        }
        if (t == 0) { knn_idx[(size_t)g*NK + s] = bbi; dist[bbi] = FLT_MAX; }
        __syncthreads();
    }
}

// ---------------------------------------------------------------- weight repack (w1 -> stride 68, zero-pad col 67)
__global__ void repack_w1(const float* __restrict__ w1, float* __restrict__ w1p) {
    int e = threadIdx.x + blockIdx.x * blockDim.x;
    if (e < 64*68) {
        int o = e / 68, c = e - o*68;
        w1p[e] = (c < 67) ? w1[o*67 + c] : 0.f;
    }
}

// ---------------------------------------------------------------- BN finalize: a = g*rsqrt(var+eps), s = be - mean*a
__global__ void finalize_kernel(const float* __restrict__ gstats, const float* __restrict__ gamma,
                                const float* __restrict__ beta, float* __restrict__ a_out,
                                float* __restrict__ s_out, int C) {
    int c = threadIdx.x + blockIdx.x * blockDim.x;
    if (c < C) {
        float mean = gstats[c] * (1.0f / CNT);
        float var  = gstats[C + c] * (1.0f / CNT) - mean * mean;
        float a = gamma[c] * rsqrtf(var + EPSV);
        a_out[c] = a;
        s_out[c] = beta[c] - mean * a;
    }
}

// ---------------------------------------------------------------- fused per-group chain
// STAGE==1: compute z1, accumulate stats.  STAGE==2: ->h1->z2 stats.
// STAGE==3: ->h2->z3 stats.  STAGE==4: full chain -> maxpool -> out.
template<int STAGE>
__global__ __launch_bounds__(256) void chain_kernel(
    const float* __restrict__ xyz, const float* __restrict__ points,
    const float* __restrict__ newxyz, const int* __restrict__ knn_idx,
    const float* __restrict__ w1p, const float* __restrict__ b1,
    const float* __restrict__ w2,  const float* __restrict__ b2,
    const float* __restrict__ w3,  const float* __restrict__ b3,
    const float* __restrict__ ab,   // a1[64] s1[64] a2[64] s2[64] a3[128] s3[128]
    float* __restrict__ gstats,     // [sum C][sq C] for this stage
    float* __restrict__ out_np)
{
    __shared__ __align__(16) float feat[32][72];
    __shared__ __align__(16) float hbuf[32][72];
    __shared__ float lsum[128], lsq[128];
    __shared__ int kidx[32];
    const int t = threadIdx.x;
    const int rowg = t & 7;        // 8 row groups x 4 rows
    const int colg = t >> 3;       // 32 col groups

    if (STAGE < 4) {
        if (t < 128) { lsum[t] = 0.f; lsq[t] = 0.f; }
    }
    float bias1[2], a1v[2], s1v[2], bias2[2], a2v[2], s2v[2], bias3[4], a3v[4], s3v[4];
#pragma unroll
    for (int j = 0; j < 2; ++j) {
        int c = colg*2 + j;
        bias1[j] = b1[c];
        bias2[j] = b2[c];
        if (STAGE >= 2) { a1v[j] = ab[c];      s1v[j] = ab[64 + c]; }
        if (STAGE >= 3) { a2v[j] = ab[128 + c]; s2v[j] = ab[192 + c]; }
    }
#pragma unroll
    for (int j = 0; j < 4; ++j) {
        int c = colg*4 + j;
        bias3[j] = b3[c];
        if (STAGE >= 4) { a3v[j] = ab[256 + c]; s3v[j] = ab[384 + c]; }
    }

    for (int g = blockIdx.x; g < NB*NM; g += gridDim.x) {
        const int b = g >> 10, m = g & (NM-1);
        __syncthreads();                                   // protect feat/hbuf/kidx reuse
        if (t < 32) kidx[t] = knn_idx[(size_t)g*NK + t];
        __syncthreads();
        {   // gather features: [norm(3) | points(64)], pad col 67 = 0
            const float* pb = points + (size_t)b * NP * CIN;
#pragma unroll
            for (int e = t; e < 32*CIN; e += 256) {
                int r = e >> 6, c = e & 63;
                feat[r][3 + c] = pb[(size_t)kidx[r]*CIN + c];
            }
            const float* xb = xyz + (size_t)b * NP * 3;
            size_t co = ((size_t)b*NM + m) * 3;
            if (t < 96) {
                int r = t / 3, d = t - 3*r;
                feat[r][d] = xb[kidx[r]*3 + d] - newxyz[co + d];
            }
            if (t < 32) feat[t][67] = 0.f;
        }
        __syncthreads();

        // ---- layer 1: K=68 (17 x float4), out 32x64, TM=4 TN=2
        float acc[4][2];
#pragma unroll
        for (int i = 0; i < 4; ++i) { acc[i][0] = bias1[0]; acc[i][1] = bias1[1]; }
        {
            const float* wr0 = w1p + (size_t)(colg*2+0)*68;
            const float* wr1 = w1p + (size_t)(colg*2+1)*68;
            for (int c4 = 0; c4 < 17; ++c4) {
                float4 w0 = *(const float4*)(wr0 + c4*4);
                float4 w1v = *(const float4*)(wr1 + c4*4);
#pragma unroll
                for (int i = 0; i < 4; ++i) {
                    float4 f = *(const float4*)(&feat[rowg*4+i][c4*4]);
                    acc[i][0] += f.x*w0.x + f.y*w0.y + f.z*w0.z + f.w*w0.w;
                    acc[i][1] += f.x*w1v.x + f.y*w1v.y + f.z*w1v.z + f.w*w1v.w;
                }
            }
        }
        if (STAGE == 1) {
#pragma unroll
            for (int j = 0; j < 2; ++j) {
                float p = acc[0][j]+acc[1][j]+acc[2][j]+acc[3][j];
                float q = acc[0][j]*acc[0][j]+acc[1][j]*acc[1][j]+acc[2][j]*acc[2][j]+acc[3][j]*acc[3][j];
#pragma unroll
                for (int off = 4; off > 0; off >>= 1) { p += __shfl_down(p, off, 8); q += __shfl_down(q, off, 8); }
                if (rowg == 0) { int c = colg*2+j; lsum[c] += p; lsq[c] += q; }
            }
            continue;
        }
        // h1 = relu(bn(z1))
#pragma unroll
        for (int i = 0; i < 4; ++i)
#pragma unroll
            for (int j = 0; j < 2; ++j)
                hbuf[rowg*4+i][colg*2+j] = fmaxf(acc[i][j]*a1v[j] + s1v[j], 0.f);
        __syncthreads();

        // ---- layer 2: K=64 (16 x float4)
#pragma unroll
        for (int i = 0; i < 4; ++i) { acc[i][0] = bias2[0]; acc[i][1] = bias2[1]; }
        {
            const float* wr0 = w2 + (size_t)(colg*2+0)*64;
            const float* wr1 = w2 + (size_t)(colg*2+1)*64;
            for (int c4 = 0; c4 < 16; ++c4) {
                float4 w0 = *(const float4*)(wr0 + c4*4);
                float4 w1v = *(const float4*)(wr1 + c4*4);
#pragma unroll
                for (int i = 0; i < 4; ++i) {
                    float4 f = *(const float4*)(&hbuf[rowg*4+i][c4*4]);
                    acc[i][0] += f.x*w0.x + f.y*w0.y + f.z*w0.z + f.w*w0.w;
                    acc[i][1] += f.x*w1v.x + f.y*w1v.y + f.z*w1v.z + f.w*w1v.w;
                }
            }
        }
        if (STAGE == 2) {
#pragma unroll
            for (int j = 0; j < 2; ++j) {
                float p = acc[0][j]+acc[1][j]+acc[2][j]+acc[3][j];
                float q = acc[0][j]*acc[0][j]+acc[1][j]*acc[1][j]+acc[2][j]*acc[2][j]+acc[3][j]*acc[3][j];
#pragma unroll
                for (int off = 4; off > 0; off >>= 1) { p += __shfl_down(p, off, 8); q += __shfl_down(q, off, 8); }
                if (rowg == 0) { int c = colg*2+j; lsum[c] += p; lsq[c] += q; }
            }
            continue;
        }
        __syncthreads();            // all layer-2 reads of hbuf done before overwrite
#pragma unroll
        for (int i = 0; i < 4; ++i)
#pragma unroll
            for (int j = 0; j < 2; ++j)
                hbuf[rowg*4+i][colg*2+j] = fmaxf(acc[i][j]*a2v[j] + s2v[j], 0.f);
        __syncthreads();

        // ---- layer 3: K=64, out 32x128, TM=4 TN=4
        float acc3[4][4];
#pragma unroll
        for (int i = 0; i < 4; ++i)
#pragma unroll
            for (int j = 0; j < 4; ++j) acc3[i][j] = bias3[j];
        {
            const float* wra = w3 + (size_t)(colg*4+0)*64;
            const float* wrb = w3 + (size_t)(colg*4+1)*64;
            const float* wrc = w3 + (size_t)(colg*4+2)*64;
            const float* wrd = w3 + (size_t)(colg*4+3)*64;
            for (int c4 = 0; c4 < 16; ++c4) {
                float4 wa = *(const float4*)(wra + c4*4);
                float4 wb = *(const float4*)(wrb + c4*4);
                float4 wc = *(const float4*)(wrc + c4*4);
                float4 wd = *(const float4*)(wrd + c4*4);
#pragma unroll
                for (int i = 0; i < 4; ++i) {
                    float4 f = *(const float4*)(&hbuf[rowg*4+i][c4*4]);
                    acc3[i][0] += f.x*wa.x + f.y*wa.y + f.z*wa.z + f.w*wa.w;
                    acc3[i][1] += f.x*wb.x + f.y*wb.y + f.z*wb.z + f.w*wb.w;
                    acc3[i][2] += f.x*wc.x + f.y*wc.y + f.z*wc.z + f.w*wc.w;
                    acc3[i][3] += f.x*wd.x + f.y*wd.y + f.z*wd.z + f.w*wd.w;
                }
            }
        }
        if (STAGE == 3) {
#pragma unroll
            for (int j = 0; j < 4; ++j) {
                float p = acc3[0][j]+acc3[1][j]+acc3[2][j]+acc3[3][j];
                float q = acc3[0][j]*acc3[0][j]+acc3[1][j]*acc3[1][j]+acc3[2][j]*acc3[2][j]+acc3[3][j]*acc3[3][j];
#pragma unroll
                for (int off = 4; off > 0; off >>= 1) { p += __shfl_down(p, off, 8); q += __shfl_down(q, off, 8); }
                if (rowg == 0) { int c = colg*4+j; lsum[c] += p; lsq[c] += q; }
            }
            continue;
        }
        // STAGE 4: bn+relu, max over 32 rows, write output
        float mx[4];
#pragma unroll
        for (int j = 0; j < 4; ++j) {
            float h0 = fmaxf(acc3[0][j]*a3v[j] + s3v[j], 0.f);
            float h1 = fmaxf(acc3[1][j]*a3v[j] + s3v[j], 0.f);
            float h2 = fmaxf(acc3[2][j]*a3v[j] + s3v[j], 0.f);
            float h3 = fmaxf(acc3[3][j]*a3v[j] + s3v[j], 0.f);
            mx[j] = fmaxf(fmaxf(h0, h1), fmaxf(h2, h3));
        }
#pragma unroll
        for (int off = 4; off > 0; off >>= 1) {
#pragma unroll
            for (int j = 0; j < 4; ++j) mx[j] = fmaxf(mx[j], __shfl_down(mx[j], off, 8));
        }
        if (rowg == 0) {
            float4 v = make_float4(mx[0], mx[1], mx[2], mx[3]);
            *(float4*)(out_np + (size_t)g*C3 + colg*4) = v;
        }
    }
    if (STAGE < 4) {
        __syncthreads();
        const int C = (STAGE == 3) ? 128 : 64;
        if (t < C) { atomicAdd(&gstats[t], lsum[t]); atomicAdd(&gstats[C + t], lsq[t]); }
    }
}

// ---------------------------------------------------------------- launch
extern "C" void kernel_launch(void* const* d_in, const int* in_sizes, int n_in,
                              void* d_out, int out_size, void* d_ws, size_t ws_size,
                              hipStream_t stream) {
    (void)in_sizes; (void)n_in; (void)out_size; (void)ws_size;
    const float* xyz    = (const float*)d_in[0];
    const float* points = (const float*)d_in[1];
    const float* w1  = (const float*)d_in[2];
    const float* b1  = (const float*)d_in[3];
    const float* g1  = (const float*)d_in[4];
    const float* be1 = (const float*)d_in[5];
    const float* w2  = (const float*)d_in[6];
    const float* b2  = (const float*)d_in[7];
    const float* g2  = (const float*)d_in[8];
    const float* be2 = (const float*)d_in[9];
    const float* w3  = (const float*)d_in[10];
    const float* b3  = (const float*)d_in[11];
    const float* g3  = (const float*)d_in[12];
    const float* be3 = (const float*)d_in[13];

    float* out = (float*)d_out;
    float* newxyz = out;                          // (B,M,3)
    float* out_np = out + (size_t)NB*NM*3;        // (B,M,128)

    int*   fps_idx = (int*)d_ws;                                  // NB*NM
    int*   knn_idx = fps_idx + NB*NM;                             // NB*NM*NK
    float* stats   = (float*)(knn_idx + (size_t)NB*NM*NK);        // 512 f
    float* ab      = stats + 512;                                 // 512 f
    float* w1p     = ab + 512;                                    // 64*68 f

    hipMemsetAsync(stats, 0, 512*sizeof(float), stream);
    repack_w1<<<17, 256, 0, stream>>>(w1, w1p);
    fps_kernel<<<NB, 512, 0, stream>>>(xyz, fps_idx, newxyz);
    knn_kernel<<<NB*NM, 256, 0, stream>>>(xyz, newxyz, knn_idx);

    chain_kernel<1><<<2048, 256, 0, stream>>>(xyz, points, newxyz, knn_idx, w1p, b1, w2, b2, w3, b3,
                                              ab, stats + 0, out_np);
    finalize_kernel<<<1, 64, 0, stream>>>(stats + 0, g1, be1, ab + 0, ab + 64, 64);
    chain_kernel<2><<<2048, 256, 0, stream>>>(xyz, points, newxyz, knn_idx, w1p, b1, w2, b2, w3, b3,
                                              ab, stats + 128, out_np);
    finalize_kernel<<<1, 64, 0, stream>>>(stats + 128, g2, be2, ab + 128, ab + 192, 64);
    chain_kernel<3><<<2048, 256, 0, stream>>>(xyz, points, newxyz, knn_idx, w1p, b1, w2, b2, w3, b3,
                                              ab, stats + 256, out_np);
    finalize_kernel<<<1, 128, 0, stream>>>(stats + 256, g3, be3, ab + 256, ab + 384, 128);
    chain_kernel<4><<<2048, 256, 0, stream>>>(xyz, points, newxyz, knn_idx, w1p, b1, w2, b2, w3, b3,
                                              ab, stats, out_np);
}

// Round 3
// 3662.628 us; speedup vs baseline: 1.8086x; 1.8086x over previous
//
#include <hip/hip_runtime.h>
#include <float.h>

#define NB 16
#define NP 4096
#define NM 1024
#define NK 32
#define CIN 64
#define C3 128
#define NGRP (NB*NM)
#define CNT (NB*NM*NK)
#define EPSV 1e-5f

// Exact, contraction-free squared distance: matches numpy/JAX float32
// elementwise-square + left-to-right sum bit-for-bit (discrete selections
// in FPS/KNN depend on exact bit patterns).
__device__ __forceinline__ float sqdist3(float dx, float dy, float dz) {
    return __fadd_rn(__fadd_rn(__fmul_rn(dx, dx), __fmul_rn(dy, dy)), __fmul_rn(dz, dz));
}

__device__ __forceinline__ float dot4(float4 a, float4 b, float acc) {
    acc += a.x*b.x; acc += a.y*b.y; acc += a.z*b.z; acc += a.w*b.w; return acc;
}

// ---------------------------------------------------------------- FPS
__global__ __launch_bounds__(512) void fps_kernel(const float* __restrict__ xyz,
                                                  int* __restrict__ fps_idx,
                                                  float* __restrict__ newxyz) {
    const int b = blockIdx.x;
    const int t = threadIdx.x;
    const float* xb = xyz + (size_t)b * NP * 3;
    float px[8], py[8], pz[8], dist[8];
#pragma unroll
    for (int j = 0; j < 8; ++j) {
        int n = t + 512 * j;
        px[j] = xb[n*3+0]; py[j] = xb[n*3+1]; pz[j] = xb[n*3+2];
        dist[j] = 1e10f;
    }
    __shared__ float cent[3];
    __shared__ float redv[8];
    __shared__ int   redi[8];
    int cur = 0;
    for (int it = 0; it < NM; ++it) {
        if (t == (cur & 511)) {
            int j = cur >> 9;
            cent[0] = px[j]; cent[1] = py[j]; cent[2] = pz[j];
            size_t o = ((size_t)b * NM + it) * 3;
            newxyz[o+0] = px[j]; newxyz[o+1] = py[j]; newxyz[o+2] = pz[j];
            fps_idx[b*NM + it] = cur;
        }
        __syncthreads();
        float cx = cent[0], cy = cent[1], cz = cent[2];
        float best = -1.0f; int bi = 0;
#pragma unroll
        for (int j = 0; j < 8; ++j) {
            float d = sqdist3(px[j]-cx, py[j]-cy, pz[j]-cz);
            float nd = fminf(dist[j], d);
            dist[j] = nd;
            if (nd > best) { best = nd; bi = t + 512*j; }   // ascending n: > keeps lowest idx
        }
#pragma unroll
        for (int off = 32; off > 0; off >>= 1) {
            float ov = __shfl_down(best, off, 64);
            int   oi = __shfl_down(bi,   off, 64);
            if (ov > best || (ov == best && oi < bi)) { best = ov; bi = oi; }
        }
        if ((t & 63) == 0) { redv[t>>6] = best; redi[t>>6] = bi; }
        __syncthreads();
        float bv = redv[0]; int bbi = redi[0];
#pragma unroll
        for (int w = 1; w < 8; ++w) {
            float v = redv[w]; int i2 = redi[w];
            if (v > bv || (v == bv && i2 < bbi)) { bv = v; bbi = i2; }
        }
        cur = bbi;   // every thread computes identically
    }
}

// ---------------------------------------------------------------- KNN
__global__ __launch_bounds__(256) void knn_kernel(const float* __restrict__ xyz,
                                                  const float* __restrict__ newxyz,
                                                  int* __restrict__ knn_idx) {
    const int g = blockIdx.x;
    const int b = g >> 10, m = g & (NM-1);
    const int t = threadIdx.x;
    const float* xb = xyz + (size_t)b * NP * 3;
    __shared__ float dist[NP];
    __shared__ float rv[4];
    __shared__ int   ri[4];
    size_t co = ((size_t)b * NM + m) * 3;
    float cx = newxyz[co+0], cy = newxyz[co+1], cz = newxyz[co+2];
#pragma unroll
    for (int j = 0; j < 16; ++j) {
        int n = t + 256*j;
        dist[n] = sqdist3(cx - xb[n*3+0], cy - xb[n*3+1], cz - xb[n*3+2]);
    }
    __syncthreads();
    for (int s = 0; s < NK; ++s) {
        float best = FLT_MAX; int bi = 0;
#pragma unroll
        for (int j = 0; j < 16; ++j) {
            int n = t + 256*j;
            float d = dist[n];
            if (d < best) { best = d; bi = n; }     // ascending n: < keeps lowest idx
        }
#pragma unroll
        for (int off = 32; off > 0; off >>= 1) {
            float ov = __shfl_down(best, off, 64);
            int   oi = __shfl_down(bi,   off, 64);
            if (ov < best || (ov == best && oi < bi)) { best = ov; bi = oi; }
        }
        if ((t & 63) == 0) { rv[t>>6] = best; ri[t>>6] = bi; }
        __syncthreads();
        float bv = rv[0]; int bbi = ri[0];
#pragma unroll
        for (int w = 1; w < 4; ++w) {
            float v = rv[w]; int i2 = ri[w];
            if (v < bv || (v == bv && i2 < bbi)) { bv = v; bbi = i2; }
        }
        if (t == 0) { knn_idx[(size_t)g*NK + s] = bbi; dist[bbi] = FLT_MAX; }
        __syncthreads();
    }
}

// ---------------------------------------------------------------- weight pre-pack
// Global packed layout (float4): w1[17][64] | w2[16][64] | w3[16][128], k-chunk major.
// w1's input dim permuted to [points(64) | norm(3) | 0-pad] to match our feat layout.
__global__ void repack_weights(const float* __restrict__ w1, const float* __restrict__ w2,
                               const float* __restrict__ w3, float4* __restrict__ wg) {
    int id = threadIdx.x + blockIdx.x * 256;
    if (id >= 4160) return;
    float4 v;
    if (id < 1088) {
        int c4 = id >> 6, col = id & 63;
        float e[4];
#pragma unroll
        for (int l = 0; l < 4; ++l) {
            int c = c4*4 + l;
            e[l] = (c < 64) ? w1[col*67 + c + 3] : ((c < 67) ? w1[col*67 + (c - 64)] : 0.f);
        }
        v = make_float4(e[0], e[1], e[2], e[3]);
    } else if (id < 2112) {
        int i2 = id - 1088; int c4 = i2 >> 6, col = i2 & 63;
        const float* p = w2 + col*64 + c4*4;
        v = make_float4(p[0], p[1], p[2], p[3]);
    } else {
        int i3 = id - 2112; int c4 = i3 >> 7, col = i3 & 127;
        const float* p = w3 + col*64 + c4*4;
        v = make_float4(p[0], p[1], p[2], p[3]);
    }
    wg[id] = v;
}

// ---------------------------------------------------------------- BN finalize
__global__ void finalize_kernel(const float* __restrict__ gstats, const float* __restrict__ gamma,
                                const float* __restrict__ beta, float* __restrict__ a_out,
                                float* __restrict__ s_out, int C) {
    int c = threadIdx.x + blockIdx.x * blockDim.x;
    if (c < C) {
        float mean = gstats[c] * (1.0f / CNT);
        float var  = gstats[C + c] * (1.0f / CNT) - mean * mean;
        float a = gamma[c] * rsqrtf(var + EPSV);
        a_out[c] = a;
        s_out[c] = beta[c] - mean * a;
    }
}

// ---------------------------------------------------------------- fused per-group chain
// Weights LDS-resident (stage-conditional). feat/hbuf XOR-swizzled:
// phys slot = c4 ^ (row>>2); feat rows 24 f4 slots, hbuf rows 16 slots.
// Thread (rowg=t&7, colg=t>>3) computes rows rowg*4..+3, cols {colg,colg+32(,+64,+96)}.
template<int STAGE>
__global__ __launch_bounds__(256, (STAGE <= 1) ? 4 : ((STAGE == 2) ? 2 : 1))
void chain_kernel(const float* __restrict__ xyz, const float* __restrict__ points,
                  const float* __restrict__ newxyz, const int* __restrict__ knn_idx,
                  const float4* __restrict__ wg,
                  const float* __restrict__ b1, const float* __restrict__ b2,
                  const float* __restrict__ b3, const float* __restrict__ ab,
                  float* __restrict__ gstats, float* __restrict__ out_np)
{
    constexpr int W1F4 = 17*64;                       // 1088
    constexpr int W2F4 = (STAGE >= 2) ? 16*64 : 0;    // 1024
    constexpr int W3F4 = (STAGE >= 3) ? 16*128 : 0;   // 2048
    constexpr int WTOT = W1F4 + W2F4 + W3F4;
    constexpr int FEATF4 = 32*24;                     // 768 (24 slots/row)
    constexpr int HBF4 = (STAGE >= 2) ? 32*16 : 0;    // 512 (16 slots/row)
    __shared__ __align__(16) float4 smem[WTOT + FEATF4 + HBF4 + 72];  // +72f4: stats(256f)+kidx(32i)
    float4* featb = smem + WTOT;
    float*  featF = (float*)featb;
    float4* hb    = featb + FEATF4;
    float*  hbF   = (float*)hb;
    float*  statL = (float*)(smem + WTOT + FEATF4 + HBF4);
    int*    kidx  = (int*)(statL + 256);

    const int t = threadIdx.x;
    const int rowg = t & 7;
    const int colg = t >> 3;

    for (int i = t; i < WTOT; i += 256) smem[i] = wg[i];
    if (STAGE < 4) statL[t] = 0.f;

    float bias1[2], a1v[2], s1v[2], bias2[2], a2v[2], s2v[2];
    float bias3[4], a3v[4], s3v[4];
#pragma unroll
    for (int j = 0; j < 2; ++j) {
        int c = colg + 32*j;
        bias1[j] = b1[c]; bias2[j] = b2[c];
        if (STAGE >= 2) { a1v[j] = ab[c];       s1v[j] = ab[64 + c]; }
        if (STAGE >= 3) { a2v[j] = ab[128 + c]; s2v[j] = ab[192 + c]; }
    }
#pragma unroll
    for (int j = 0; j < 4; ++j) {
        int c = colg + 32*j;
        bias3[j] = b3[c];
        if (STAGE == 4) { a3v[j] = ab[256 + c]; s3v[j] = ab[384 + c]; }
    }

    for (int g = blockIdx.x; g < NGRP; g += gridDim.x) {
        const int b = g >> 10;
        __syncthreads();                               // protect smem reuse across groups
        if (t < 32) kidx[t] = knn_idx[(size_t)g*NK + t];
        __syncthreads();
        // ---- gather: points as float4 (coalesced 256B/row), then norm + pad
        const float* pb = points + (size_t)b * NP * CIN;
        {
            int r0 = t >> 4, c4g = t & 15;
            featb[r0*24 + (c4g ^ (r0>>2))] = *(const float4*)(pb + (size_t)kidx[r0]*CIN + c4g*4);
            int r1 = r0 + 16;
            featb[r1*24 + (c4g ^ (r1>>2))] = *(const float4*)(pb + (size_t)kidx[r1]*CIN + c4g*4);
        }
        const float* xb = xyz + (size_t)b * NP * 3;
        if (t < 96) {
            int r = t / 3, d = t - r*3;
            featF[r*96 + ((16 ^ (r>>2))<<2) + d] = xb[kidx[r]*3 + d] - newxyz[(size_t)g*3 + d];
        }
        if (t < 32) featF[t*96 + ((16 ^ (t>>2))<<2) + 3] = 0.f;
        __syncthreads();

        // ---- layer 1: K=68 (17 chunks)
        float acc[2][4];
#pragma unroll
        for (int i = 0; i < 4; ++i) { acc[0][i] = bias1[0]; acc[1][i] = bias1[1]; }
#pragma unroll 4
        for (int c4 = 0; c4 < 17; ++c4) {
            float4 w0 = smem[c4*64 + colg];
            float4 w1v = smem[c4*64 + colg + 32];
#pragma unroll
            for (int i = 0; i < 4; ++i) {
                float4 f = featb[(rowg*4 + i)*24 + (c4 ^ rowg)];
                acc[0][i] = dot4(f, w0, acc[0][i]);
                acc[1][i] = dot4(f, w1v, acc[1][i]);
            }
        }
        if (STAGE == 1) {
#pragma unroll
            for (int j = 0; j < 2; ++j) {
                float p = acc[j][0]+acc[j][1]+acc[j][2]+acc[j][3];
                float q = acc[j][0]*acc[j][0]+acc[j][1]*acc[j][1]+acc[j][2]*acc[j][2]+acc[j][3]*acc[j][3];
#pragma unroll
                for (int off = 4; off > 0; off >>= 1) { p += __shfl_down(p, off, 8); q += __shfl_down(q, off, 8); }
                if (rowg == 0) { int c = colg + 32*j; statL[c] += p; statL[128 + c] += q; }
            }
            continue;
        }
        // h1 -> hbuf
#pragma unroll
        for (int j = 0; j < 2; ++j) {
            int col = colg + 32*j;
            int so = (((col>>2) ^ rowg) << 2) + (col & 3);
#pragma unroll
            for (int i = 0; i < 4; ++i)
                hbF[(rowg*4 + i)*64 + so] = fmaxf(acc[j][i]*a1v[j] + s1v[j], 0.f);
        }
        __syncthreads();

        // ---- layer 2: K=64 (16 chunks), input hbuf
#pragma unroll
        for (int i = 0; i < 4; ++i) { acc[0][i] = bias2[0]; acc[1][i] = bias2[1]; }
#pragma unroll 4
        for (int c4 = 0; c4 < 16; ++c4) {
            float4 w0 = smem[W1F4 + c4*64 + colg];
            float4 w1v = smem[W1F4 + c4*64 + colg + 32];
#pragma unroll
            for (int i = 0; i < 4; ++i) {
                float4 f = hb[(rowg*4 + i)*16 + (c4 ^ rowg)];
                acc[0][i] = dot4(f, w0, acc[0][i]);
                acc[1][i] = dot4(f, w1v, acc[1][i]);
            }
        }
        if (STAGE == 2) {
#pragma unroll
            for (int j = 0; j < 2; ++j) {
                float p = acc[j][0]+acc[j][1]+acc[j][2]+acc[j][3];
                float q = acc[j][0]*acc[j][0]+acc[j][1]*acc[j][1]+acc[j][2]*acc[j][2]+acc[j][3]*acc[j][3];
#pragma unroll
                for (int off = 4; off > 0; off >>= 1) { p += __shfl_down(p, off, 8); q += __shfl_down(q, off, 8); }
                if (rowg == 0) { int c = colg + 32*j; statL[c] += p; statL[128 + c] += q; }
            }
            continue;
        }
        // h2 -> feat buffer (ping-pong; layer-1 reads finished before last barrier)
#pragma unroll
        for (int j = 0; j < 2; ++j) {
            int col = colg + 32*j;
            int so = (((col>>2) ^ rowg) << 2) + (col & 3);
#pragma unroll
            for (int i = 0; i < 4; ++i)
                featF[(rowg*4 + i)*96 + so] = fmaxf(acc[j][i]*a2v[j] + s2v[j], 0.f);
        }
        __syncthreads();

        // ---- layer 3: K=64, 128 cols (TN=4), input feat buffer
        float acc3[4][4];
#pragma unroll
        for (int i = 0; i < 4; ++i)
#pragma unroll
            for (int j = 0; j < 4; ++j) acc3[j][i] = bias3[j];
#pragma unroll 4
        for (int c4 = 0; c4 < 16; ++c4) {
            float4 wa = smem[W1F4 + W2F4 + c4*128 + colg];
            float4 wb = smem[W1F4 + W2F4 + c4*128 + colg + 32];
            float4 wc = smem[W1F4 + W2F4 + c4*128 + colg + 64];
            float4 wd = smem[W1F4 + W2F4 + c4*128 + colg + 96];
#pragma unroll
            for (int i = 0; i < 4; ++i) {
                float4 f = featb[(rowg*4 + i)*24 + (c4 ^ rowg)];
                acc3[0][i] = dot4(f, wa, acc3[0][i]);
                acc3[1][i] = dot4(f, wb, acc3[1][i]);
                acc3[2][i] = dot4(f, wc, acc3[2][i]);
                acc3[3][i] = dot4(f, wd, acc3[3][i]);
            }
        }
        if (STAGE == 3) {
#pragma unroll
            for (int j = 0; j < 4; ++j) {
                float p = acc3[j][0]+acc3[j][1]+acc3[j][2]+acc3[j][3];
                float q = acc3[j][0]*acc3[j][0]+acc3[j][1]*acc3[j][1]+acc3[j][2]*acc3[j][2]+acc3[j][3]*acc3[j][3];
#pragma unroll
                for (int off = 4; off > 0; off >>= 1) { p += __shfl_down(p, off, 8); q += __shfl_down(q, off, 8); }
                if (rowg == 0) { int c = colg + 32*j; statL[c] += p; statL[128 + c] += q; }
            }
            continue;
        }
        // ---- STAGE 4: bn+relu, max over 32 rows (4 local + 8-lane shuffle), write
        float mx[4];
#pragma unroll
        for (int j = 0; j < 4; ++j) {
            float h0 = fmaxf(acc3[j][0]*a3v[j] + s3v[j], 0.f);
            float h1 = fmaxf(acc3[j][1]*a3v[j] + s3v[j], 0.f);
            float h2 = fmaxf(acc3[j][2]*a3v[j] + s3v[j], 0.f);
            float h3 = fmaxf(acc3[j][3]*a3v[j] + s3v[j], 0.f);
            mx[j] = fmaxf(fmaxf(h0, h1), fmaxf(h2, h3));
        }
#pragma unroll
        for (int off = 4; off > 0; off >>= 1)
#pragma unroll
            for (int j = 0; j < 4; ++j) mx[j] = fmaxf(mx[j], __shfl_down(mx[j], off, 8));
        if (rowg == 0) {
#pragma unroll
            for (int j = 0; j < 4; ++j)
                out_np[(size_t)g*C3 + colg + 32*j] = mx[j];
        }
    }
    if (STAGE < 4) {
        __syncthreads();
        constexpr int C = (STAGE == 3) ? 128 : 64;
        if (t < C) { atomicAdd(&gstats[t], statL[t]); atomicAdd(&gstats[C + t], statL[128 + t]); }
    }
}

// ---------------------------------------------------------------- launch
extern "C" void kernel_launch(void* const* d_in, const int* in_sizes, int n_in,
                              void* d_out, int out_size, void* d_ws, size_t ws_size,
                              hipStream_t stream) {
    (void)in_sizes; (void)n_in; (void)out_size; (void)ws_size;
    const float* xyz    = (const float*)d_in[0];
    const float* points = (const float*)d_in[1];
    const float* w1  = (const float*)d_in[2];
    const float* b1  = (const float*)d_in[3];
    const float* g1  = (const float*)d_in[4];
    const float* be1 = (const float*)d_in[5];
    const float* w2  = (const float*)d_in[6];
    const float* b2  = (const float*)d_in[7];
    const float* g2  = (const float*)d_in[8];
    const float* be2 = (const float*)d_in[9];
    const float* w3  = (const float*)d_in[10];
    const float* b3  = (const float*)d_in[11];
    const float* g3  = (const float*)d_in[12];
    const float* be3 = (const float*)d_in[13];

    float* out = (float*)d_out;
    float* newxyz = out;                          // (B,M,3)
    float* out_np = out + (size_t)NB*NM*3;        // (B,M,128)

    int*    fps_idx = (int*)d_ws;                                 // 16384 ints
    int*    knn_idx = fps_idx + NB*NM;                            // 524288 ints
    float*  stats   = (float*)(knn_idx + (size_t)NB*NM*NK);       // 512 f
    float*  ab      = stats + 512;                                // 512 f
    float4* wg      = (float4*)(ab + 512);                        // 4160 float4 (16B-aligned offset)

    hipMemsetAsync(stats, 0, 512*sizeof(float), stream);
    repack_weights<<<17, 256, 0, stream>>>(w1, w2, w3, wg);
    fps_kernel<<<NB, 512, 0, stream>>>(xyz, fps_idx, newxyz);
    knn_kernel<<<NB*NM, 256, 0, stream>>>(xyz, newxyz, knn_idx);

    chain_kernel<1><<<1024, 256, 0, stream>>>(xyz, points, newxyz, knn_idx, wg, b1, b2, b3,
                                              ab, stats + 0, out_np);
    finalize_kernel<<<1, 64, 0, stream>>>(stats + 0, g1, be1, ab + 0, ab + 64, 64);
    chain_kernel<2><<<1024, 256, 0, stream>>>(xyz, points, newxyz, knn_idx, wg, b1, b2, b3,
                                              ab, stats + 128, out_np);
    finalize_kernel<<<1, 64, 0, stream>>>(stats + 128, g2, be2, ab + 128, ab + 192, 64);
    chain_kernel<3><<<1024, 256, 0, stream>>>(xyz, points, newxyz, knn_idx, wg, b1, b2, b3,
                                              ab, stats + 256, out_np);
    finalize_kernel<<<1, 128, 0, stream>>>(stats + 256, g3, be3, ab + 256, ab + 384, 128);
    chain_kernel<4><<<1024, 256, 0, stream>>>(xyz, points, newxyz, knn_idx, wg, b1, b2, b3,
                                              ab, stats, out_np);
}

// Round 6
// 2817.926 us; speedup vs baseline: 2.3508x; 1.2998x over previous
//
#include <hip/hip_runtime.h>
#include <float.h>

#define NB 16
#define NP 4096
#define NM 1024
#define NK 32
#define CIN 64
#define C3 128
#define NGRP (NB*NM)
#define CNT (NB*NM*NK)
#define EPSV 1e-5f

// Exact, contraction-free squared distance: matches numpy/JAX float32
// elementwise-square + left-to-right sum bit-for-bit (discrete selections
// in FPS/KNN depend on exact bit patterns).
__device__ __forceinline__ float sqdist3(float dx, float dy, float dz) {
    return __fadd_rn(__fadd_rn(__fmul_rn(dx, dx), __fmul_rn(dy, dy)), __fmul_rn(dz, dz));
}

__device__ __forceinline__ float dot4(float4 a, float4 b, float acc) {
    acc += a.x*b.x; acc += a.y*b.y; acc += a.z*b.z; acc += a.w*b.w; return acc;
}

// ---------------------------------------------------------------- FPS
// 256 threads = 4 waves. Thread t owns CONTIGUOUS points 16t..16t+15 in
// registers, so lowest-lane / lowest-wave == lowest global index and
// argmax tie-break needs no index tracking. Per iteration: register
// update loop -> value-only butterfly max -> ballot/ffs winner lane ->
// 3 shuffles pull winner coords -> one barrier + parity-buffered 4xfloat4
// cross-wave reduce. Centroid never touches LDS/global on the critical path.
__global__ __launch_bounds__(256) void fps_kernel(const float* __restrict__ xyz,
                                                  float* __restrict__ newxyz) {
    const int b = blockIdx.x;
    const int t = threadIdx.x;
    const int lane = t & 63, wv = t >> 6;
    const float* xb = xyz + (size_t)b * NP * 3;

    float px[16], py[16], pz[16], dist[16];
    {   // vectorized one-time load: 48 consecutive floats per thread
        const float4* s4 = (const float4*)(xb + t * 48);
        float4 q[12];
#pragma unroll
        for (int j = 0; j < 12; ++j) q[j] = s4[j];
        const float* f = (const float*)q;
#pragma unroll
        for (int j = 0; j < 16; ++j) {
            px[j] = f[j*3+0]; py[j] = f[j*3+1]; pz[j] = f[j*3+2];
            dist[j] = 1e10f;
        }
    }
    __shared__ float4 red[2][4];
    float cx = xb[0], cy = xb[1], cz = xb[2];   // first centroid = point 0

    for (int it = 0; it < NM; ++it) {
        if (t == 0) {
            size_t o = ((size_t)b * NM + it) * 3;
            newxyz[o+0] = cx; newxyz[o+1] = cy; newxyz[o+2] = cz;
        }
        // update running min-dist, track local best value + its coords
        float best = -1.0f, bx = 0.f, by = 0.f, bz = 0.f;
#pragma unroll
        for (int j = 0; j < 16; ++j) {
            float d = sqdist3(px[j]-cx, py[j]-cy, pz[j]-cz);
            float nd = fminf(dist[j], d);
            dist[j] = nd;
            if (nd > best) { best = nd; bx = px[j]; by = py[j]; bz = pz[j]; }  // ascending j: lowest idx
        }
        // wave max (value only)
        float wmax = best;
#pragma unroll
        for (int off = 32; off > 0; off >>= 1)
            wmax = fmaxf(wmax, __shfl_xor(wmax, off, 64));
        // lowest lane holding the max == lowest global index in this wave
        unsigned long long m = __ballot(best == wmax);
        int srcl = __ffsll((long long)m) - 1;
        float wx = __shfl(bx, srcl, 64);
        float wy = __shfl(by, srcl, 64);
        float wz = __shfl(bz, srcl, 64);
        if (lane == 0) red[it & 1][wv] = make_float4(wmax, wx, wy, wz);
        __syncthreads();
        float4 r = red[it & 1][0];
        float bv = r.x; cx = r.y; cy = r.z; cz = r.w;
#pragma unroll
        for (int w = 1; w < 4; ++w) {
            float4 rw = red[it & 1][w];
            if (rw.x > bv) { bv = rw.x; cx = rw.y; cy = rw.z; cz = rw.w; }  // strict >: lowest wave wins ties
        }
    }
}

// ---------------------------------------------------------------- KNN
__global__ __launch_bounds__(256) void knn_kernel(const float* __restrict__ xyz,
                                                  const float* __restrict__ newxyz,
                                                  int* __restrict__ knn_idx) {
    const int g = blockIdx.x;
    const int b = g >> 10, m = g & (NM-1);
    const int t = threadIdx.x;
    const float* xb = xyz + (size_t)b * NP * 3;
    __shared__ float dist[NP];
    __shared__ float rv[4];
    __shared__ int   ri[4];
    size_t co = ((size_t)b * NM + m) * 3;
    float cx = newxyz[co+0], cy = newxyz[co+1], cz = newxyz[co+2];
#pragma unroll
    for (int j = 0; j < 16; ++j) {
        int n = t + 256*j;
        dist[n] = sqdist3(cx - xb[n*3+0], cy - xb[n*3+1], cz - xb[n*3+2]);
    }
    __syncthreads();
    for (int s = 0; s < NK; ++s) {
        float best = FLT_MAX; int bi = 0;
#pragma unroll
        for (int j = 0; j < 16; ++j) {
            int n = t + 256*j;
            float d = dist[n];
            if (d < best) { best = d; bi = n; }     // ascending n: < keeps lowest idx
        }
#pragma unroll
        for (int off = 32; off > 0; off >>= 1) {
            float ov = __shfl_down(best, off, 64);
            int   oi = __shfl_down(bi,   off, 64);
            if (ov < best || (ov == best && oi < bi)) { best = ov; bi = oi; }
        }
        if ((t & 63) == 0) { rv[t>>6] = best; ri[t>>6] = bi; }
        __syncthreads();
        float bv = rv[0]; int bbi = ri[0];
#pragma unroll
        for (int w = 1; w < 4; ++w) {
            float v = rv[w]; int i2 = ri[w];
            if (v < bv || (v == bv && i2 < bbi)) { bv = v; bbi = i2; }
        }
        if (t == 0) { knn_idx[(size_t)g*NK + s] = bbi; dist[bbi] = FLT_MAX; }
        __syncthreads();
    }
}

// ---------------------------------------------------------------- weight pre-pack
// Global packed layout (float4): w1[17][64] | w2[16][64] | w3[16][128], k-chunk major.
// w1's input dim permuted to [points(64) | norm(3) | 0-pad] to match our feat layout.
__global__ void repack_weights(const float* __restrict__ w1, const float* __restrict__ w2,
                               const float* __restrict__ w3, float4* __restrict__ wg) {
    int id = threadIdx.x + blockIdx.x * 256;
    if (id >= 4160) return;
    float4 v;
    if (id < 1088) {
        int c4 = id >> 6, col = id & 63;
        float e[4];
#pragma unroll
        for (int l = 0; l < 4; ++l) {
            int c = c4*4 + l;
            e[l] = (c < 64) ? w1[col*67 + c + 3] : ((c < 67) ? w1[col*67 + (c - 64)] : 0.f);
        }
        v = make_float4(e[0], e[1], e[2], e[3]);
    } else if (id < 2112) {
        int i2 = id - 1088; int c4 = i2 >> 6, col = i2 & 63;
        const float* p = w2 + col*64 + c4*4;
        v = make_float4(p[0], p[1], p[2], p[3]);
    } else {
        int i3 = id - 2112; int c4 = i3 >> 7, col = i3 & 127;
        const float* p = w3 + col*64 + c4*4;
        v = make_float4(p[0], p[1], p[2], p[3]);
    }
    wg[id] = v;
}

// ---------------------------------------------------------------- BN finalize
__global__ void finalize_kernel(const float* __restrict__ gstats, const float* __restrict__ gamma,
                                const float* __restrict__ beta, float* __restrict__ a_out,
                                float* __restrict__ s_out, int C) {
    int c = threadIdx.x + blockIdx.x * blockDim.x;
    if (c < C) {
        float mean = gstats[c] * (1.0f / CNT);
        float var  = gstats[C + c] * (1.0f / CNT) - mean * mean;
        float a = gamma[c] * rsqrtf(var + EPSV);
        a_out[c] = a;
        s_out[c] = beta[c] - mean * a;
    }
}

// ---------------------------------------------------------------- fused per-group chain
// Weights LDS-resident (stage-conditional). feat/hbuf XOR-swizzled:
// phys slot = c4 ^ (row>>2); feat rows 24 f4 slots, hbuf rows 16 slots.
// Thread (rowg=t&7, colg=t>>3) computes rows rowg*4..+3, cols {colg,colg+32(,+64,+96)}.
template<int STAGE>
__global__ __launch_bounds__(256, (STAGE <= 1) ? 4 : ((STAGE == 2) ? 2 : 1))
void chain_kernel(const float* __restrict__ xyz, const float* __restrict__ points,
                  const float* __restrict__ newxyz, const int* __restrict__ knn_idx,
                  const float4* __restrict__ wg,
                  const float* __restrict__ b1, const float* __restrict__ b2,
                  const float* __restrict__ b3, const float* __restrict__ ab,
                  float* __restrict__ gstats, float* __restrict__ out_np)
{
    constexpr int W1F4 = 17*64;                       // 1088
    constexpr int W2F4 = (STAGE >= 2) ? 16*64 : 0;    // 1024
    constexpr int W3F4 = (STAGE >= 3) ? 16*128 : 0;   // 2048
    constexpr int WTOT = W1F4 + W2F4 + W3F4;
    constexpr int FEATF4 = 32*24;                     // 768 (24 slots/row)
    constexpr int HBF4 = (STAGE >= 2) ? 32*16 : 0;    // 512 (16 slots/row)
    __shared__ __align__(16) float4 smem[WTOT + FEATF4 + HBF4 + 72];  // +72f4: stats(256f)+kidx(32i)
    float4* featb = smem + WTOT;
    float*  featF = (float*)featb;
    float4* hb    = featb + FEATF4;
    float*  hbF   = (float*)hb;
    float*  statL = (float*)(smem + WTOT + FEATF4 + HBF4);
    int*    kidx  = (int*)(statL + 256);

    const int t = threadIdx.x;
    const int rowg = t & 7;
    const int colg = t >> 3;

    for (int i = t; i < WTOT; i += 256) smem[i] = wg[i];
    if (STAGE < 4) statL[t] = 0.f;

    float bias1[2], a1v[2], s1v[2], bias2[2], a2v[2], s2v[2];
    float bias3[4], a3v[4], s3v[4];
#pragma unroll
    for (int j = 0; j < 2; ++j) {
        int c = colg + 32*j;
        bias1[j] = b1[c]; bias2[j] = b2[c];
        if (STAGE >= 2) { a1v[j] = ab[c];       s1v[j] = ab[64 + c]; }
        if (STAGE >= 3) { a2v[j] = ab[128 + c]; s2v[j] = ab[192 + c]; }
    }
#pragma unroll
    for (int j = 0; j < 4; ++j) {
        int c = colg + 32*j;
        bias3[j] = b3[c];
        if (STAGE == 4) { a3v[j] = ab[256 + c]; s3v[j] = ab[384 + c]; }
    }

    for (int g = blockIdx.x; g < NGRP; g += gridDim.x) {
        const int b = g >> 10;
        __syncthreads();                               // protect smem reuse across groups
        if (t < 32) kidx[t] = knn_idx[(size_t)g*NK + t];
        __syncthreads();
        // ---- gather: points as float4 (coalesced 256B/row), then norm + pad
        const float* pb = points + (size_t)b * NP * CIN;
        {
            int r0 = t >> 4, c4g = t & 15;
            featb[r0*24 + (c4g ^ (r0>>2))] = *(const float4*)(pb + (size_t)kidx[r0]*CIN + c4g*4);
            int r1 = r0 + 16;
            featb[r1*24 + (c4g ^ (r1>>2))] = *(const float4*)(pb + (size_t)kidx[r1]*CIN + c4g*4);
        }
        const float* xb = xyz + (size_t)b * NP * 3;
        if (t < 96) {
            int r = t / 3, d = t - r*3;
            featF[r*96 + ((16 ^ (r>>2))<<2) + d] = xb[kidx[r]*3 + d] - newxyz[(size_t)g*3 + d];
        }
        if (t < 32) featF[t*96 + ((16 ^ (t>>2))<<2) + 3] = 0.f;
        __syncthreads();

        // ---- layer 1: K=68 (17 chunks)
        float acc[2][4];
#pragma unroll
        for (int i = 0; i < 4; ++i) { acc[0][i] = bias1[0]; acc[1][i] = bias1[1]; }
#pragma unroll 4
        for (int c4 = 0; c4 < 17; ++c4) {
            float4 w0 = smem[c4*64 + colg];
            float4 w1v = smem[c4*64 + colg + 32];
#pragma unroll
            for (int i = 0; i < 4; ++i) {
                float4 f = featb[(rowg*4 + i)*24 + (c4 ^ rowg)];
                acc[0][i] = dot4(f, w0, acc[0][i]);
                acc[1][i] = dot4(f, w1v, acc[1][i]);
            }
        }
        if (STAGE == 1) {
#pragma unroll
            for (int j = 0; j < 2; ++j) {
                float p = acc[j][0]+acc[j][1]+acc[j][2]+acc[j][3];
                float q = acc[j][0]*acc[j][0]+acc[j][1]*acc[j][1]+acc[j][2]*acc[j][2]+acc[j][3]*acc[j][3];
#pragma unroll
                for (int off = 4; off > 0; off >>= 1) { p += __shfl_down(p, off, 8); q += __shfl_down(q, off, 8); }
                if (rowg == 0) { int c = colg + 32*j; statL[c] += p; statL[128 + c] += q; }
            }
            continue;
        }
        // h1 -> hbuf
#pragma unroll
        for (int j = 0; j < 2; ++j) {
            int col = colg + 32*j;
            int so = (((col>>2) ^ rowg) << 2) + (col & 3);
#pragma unroll
            for (int i = 0; i < 4; ++i)
                hbF[(rowg*4 + i)*64 + so] = fmaxf(acc[j][i]*a1v[j] + s1v[j], 0.f);
        }
        __syncthreads();

        // ---- layer 2: K=64 (16 chunks), input hbuf
#pragma unroll
        for (int i = 0; i < 4; ++i) { acc[0][i] = bias2[0]; acc[1][i] = bias2[1]; }
#pragma unroll 4
        for (int c4 = 0; c4 < 16; ++c4) {
            float4 w0 = smem[W1F4 + c4*64 + colg];
            float4 w1v = smem[W1F4 + c4*64 + colg + 32];
#pragma unroll
            for (int i = 0; i < 4; ++i) {
                float4 f = hb[(rowg*4 + i)*16 + (c4 ^ rowg)];
                acc[0][i] = dot4(f, w0, acc[0][i]);
                acc[1][i] = dot4(f, w1v, acc[1][i]);
            }
        }
        if (STAGE == 2) {
#pragma unroll
            for (int j = 0; j < 2; ++j) {
                float p = acc[j][0]+acc[j][1]+acc[j][2]+acc[j][3];
                float q = acc[j][0]*acc[j][0]+acc[j][1]*acc[j][1]+acc[j][2]*acc[j][2]+acc[j][3]*acc[j][3];
#pragma unroll
                for (int off = 4; off > 0; off >>= 1) { p += __shfl_down(p, off, 8); q += __shfl_down(q, off, 8); }
                if (rowg == 0) { int c = colg + 32*j; statL[c] += p; statL[128 + c] += q; }
            }
            continue;
        }
        // h2 -> feat buffer (ping-pong; layer-1 reads finished before last barrier)
#pragma unroll
        for (int j = 0; j < 2; ++j) {
            int col = colg + 32*j;
            int so = (((col>>2) ^ rowg) << 2) + (col & 3);
#pragma unroll
            for (int i = 0; i < 4; ++i)
                featF[(rowg*4 + i)*96 + so] = fmaxf(acc[j][i]*a2v[j] + s2v[j], 0.f);
        }
        __syncthreads();

        // ---- layer 3: K=64, 128 cols (TN=4), input feat buffer
        float acc3[4][4];
#pragma unroll
        for (int i = 0; i < 4; ++i)
#pragma unroll
            for (int j = 0; j < 4; ++j) acc3[j][i] = bias3[j];
#pragma unroll 4
        for (int c4 = 0; c4 < 16; ++c4) {
            float4 wa = smem[W1F4 + W2F4 + c4*128 + colg];
            float4 wb = smem[W1F4 + W2F4 + c4*128 + colg + 32];
            float4 wc = smem[W1F4 + W2F4 + c4*128 + colg + 64];
            float4 wd = smem[W1F4 + W2F4 + c4*128 + colg + 96];
#pragma unroll
            for (int i = 0; i < 4; ++i) {
                float4 f = featb[(rowg*4 + i)*24 + (c4 ^ rowg)];
                acc3[0][i] = dot4(f, wa, acc3[0][i]);
                acc3[1][i] = dot4(f, wb, acc3[1][i]);
                acc3[2][i] = dot4(f, wc, acc3[2][i]);
                acc3[3][i] = dot4(f, wd, acc3[3][i]);
            }
        }
        if (STAGE == 3) {
#pragma unroll
            for (int j = 0; j < 4; ++j) {
                float p = acc3[j][0]+acc3[j][1]+acc3[j][2]+acc3[j][3];
                float q = acc3[j][0]*acc3[j][0]+acc3[j][1]*acc3[j][1]+acc3[j][2]*acc3[j][2]+acc3[j][3]*acc3[j][3];
#pragma unroll
                for (int off = 4; off > 0; off >>= 1) { p += __shfl_down(p, off, 8); q += __shfl_down(q, off, 8); }
                if (rowg == 0) { int c = colg + 32*j; statL[c] += p; statL[128 + c] += q; }
            }
            continue;
        }
        // ---- STAGE 4: bn+relu, max over 32 rows (4 local + 8-lane shuffle), write
        float mx[4];
#pragma unroll
        for (int j = 0; j < 4; ++j) {
            float h0 = fmaxf(acc3[j][0]*a3v[j] + s3v[j], 0.f);
            float h1 = fmaxf(acc3[j][1]*a3v[j] + s3v[j], 0.f);
            float h2 = fmaxf(acc3[j][2]*a3v[j] + s3v[j], 0.f);
            float h3 = fmaxf(acc3[j][3]*a3v[j] + s3v[j], 0.f);
            mx[j] = fmaxf(fmaxf(h0, h1), fmaxf(h2, h3));
        }
#pragma unroll
        for (int off = 4; off > 0; off >>= 1)
#pragma unroll
            for (int j = 0; j < 4; ++j) mx[j] = fmaxf(mx[j], __shfl_down(mx[j], off, 8));
        if (rowg == 0) {
#pragma unroll
            for (int j = 0; j < 4; ++j)
                out_np[(size_t)g*C3 + colg + 32*j] = mx[j];
        }
    }
    if (STAGE < 4) {
        __syncthreads();
        constexpr int C = (STAGE == 3) ? 128 : 64;
        if (t < C) { atomicAdd(&gstats[t], statL[t]); atomicAdd(&gstats[C + t], statL[128 + t]); }
    }
}

// ---------------------------------------------------------------- launch
extern "C" void kernel_launch(void* const* d_in, const int* in_sizes, int n_in,
                              void* d_out, int out_size, void* d_ws, size_t ws_size,
                              hipStream_t stream) {
    (void)in_sizes; (void)n_in; (void)out_size; (void)ws_size;
    const float* xyz    = (const float*)d_in[0];
    const float* points = (const float*)d_in[1];
    const float* w1  = (const float*)d_in[2];
    const float* b1  = (const float*)d_in[3];
    const float* g1  = (const float*)d_in[4];
    const float* be1 = (const float*)d_in[5];
    const float* w2  = (const float*)d_in[6];
    const float* b2  = (const float*)d_in[7];
    const float* g2  = (const float*)d_in[8];
    const float* be2 = (const float*)d_in[9];
    const float* w3  = (const float*)d_in[10];
    const float* b3  = (const float*)d_in[11];
    const float* g3  = (const float*)d_in[12];
    const float* be3 = (const float*)d_in[13];

    float* out = (float*)d_out;
    float* newxyz = out;                          // (B,M,3)
    float* out_np = out + (size_t)NB*NM*3;        // (B,M,128)

    int*    knn_idx = (int*)d_ws;                                 // 524288 ints
    float*  stats   = (float*)(knn_idx + (size_t)NB*NM*NK);       // 512 f
    float*  ab      = stats + 512;                                // 512 f
    float4* wg      = (float4*)(ab + 512);                        // 4160 float4 (16B-aligned offset)

    hipMemsetAsync(stats, 0, 512*sizeof(float), stream);
    repack_weights<<<17, 256, 0, stream>>>(w1, w2, w3, wg);
    fps_kernel<<<NB, 256, 0, stream>>>(xyz, newxyz);
    knn_kernel<<<NB*NM, 256, 0, stream>>>(xyz, newxyz, knn_idx);

    chain_kernel<1><<<1024, 256, 0, stream>>>(xyz, points, newxyz, knn_idx, wg, b1, b2, b3,
                                              ab, stats + 0, out_np);
    finalize_kernel<<<1, 64, 0, stream>>>(stats + 0, g1, be1, ab + 0, ab + 64, 64);
    chain_kernel<2><<<1024, 256, 0, stream>>>(xyz, points, newxyz, knn_idx, wg, b1, b2, b3,
                                              ab, stats + 128, out_np);
    finalize_kernel<<<1, 64, 0, stream>>>(stats + 128, g2, be2, ab + 128, ab + 192, 64);
    chain_kernel<3><<<1024, 256, 0, stream>>>(xyz, points, newxyz, knn_idx, wg, b1, b2, b3,
                                              ab, stats + 256, out_np);
    finalize_kernel<<<1, 128, 0, stream>>>(stats + 256, g3, be3, ab + 256, ab + 384, 128);
    chain_kernel<4><<<1024, 256, 0, stream>>>(xyz, points, newxyz, knn_idx, wg, b1, b2, b3,
                                              ab, stats, out_np);
}